// Round 1
// baseline (975.724 us; speedup 1.0000x reference)
//
#include <hip/hip_runtime.h>

// LearnableChannelSplit: 1x1 conv (512->128) -> ReLU -> 1x1 conv (128->2)
// -> softmax over the 2 channels -> x0 = x*m0, x1 = x*m1.
// Outputs concatenated: x0 (75497472), x1 (75497472), m (294912), all fp32.

#define BB   16
#define CC   512
#define HH   96
#define WW   96
#define HWP  (HH * WW)          // 9216
#define CHN  128
#define XSZ  (BB * CC * HWP)    // 75497472

#define KC   32                 // K-chunk (input channels per LDS stage)
#define PXT  128                // pixels per block

// ---------------------------------------------------------------------------
// Kernel 1: compute m = softmax over the 2 logit channels, per pixel.
// Block: 256 threads, tile = 128 pixels x 128 hidden channels.
// Thread t: pixels px0..px0+7 (px0 = (t&15)*8), hidden o0..o0+7 (o0 = (t>>4)*8)
// -> 8x8 fp32 register tile, K staged through LDS in chunks of 32.
// Epilogue: +b1, ReLU, dot with w2 rows -> partial logits -> LDS reduction
// over the 16 o-groups -> softmax -> write m.
// ---------------------------------------------------------------------------
__global__ __launch_bounds__(256) void mask_head_kernel(
    const float* __restrict__ x, const float* __restrict__ w1,
    const float* __restrict__ b1, const float* __restrict__ w2,
    const float* __restrict__ b2, float* __restrict__ mout)
{
    __shared__ __align__(16) float smem[KC * PXT + KC * CHN];  // 32 KB
    float* xs  = smem;             // [KC][PXT]
    float* ws  = smem + KC * PXT;  // [KC][CHN]  (w1 transposed: [c][o])
    float* red = smem;             // [16][PXT][2] overlays xs (16 KB) later

    const int t   = threadIdx.x;
    const int p0  = blockIdx.x * PXT;     // 9216 % 128 == 0 -> never straddles b
    const int b   = p0 / HWP;
    const int hw0 = p0 - b * HWP;

    const int px0 = (t & 15) * 8;
    const int og  = t >> 4;               // 0..15
    const int o0  = og * 8;

    float acc[8][8];
    #pragma unroll
    for (int i = 0; i < 8; ++i)
        #pragma unroll
        for (int j = 0; j < 8; ++j) acc[i][j] = 0.0f;

    const int lpx = (t & 31) * 4;         // x-stage: float4 along pixels
    const int cst = t >> 5;               // 0..7
    const int ow  = t >> 1;               // w-stage: one hidden channel
    const int cbw = (t & 1) * 16;         // 16 contiguous c per thread

    for (int c0 = 0; c0 < CC; c0 += KC) {
        __syncthreads();
        // stage x tile: 32 c x 128 px (coalesced float4 along hw)
        #pragma unroll
        for (int r = 0; r < 4; ++r) {
            const int c = cst + r * 8;
            const float4 v =
                *(const float4*)&x[(b * CC + c0 + c) * HWP + hw0 + lpx];
            *(float4*)&xs[c * PXT + lpx] = v;
        }
        // stage w1 tile transposed: ws[c][o]
        {
            const float* wrow = &w1[ow * CC + c0 + cbw];
            #pragma unroll
            for (int k = 0; k < 16; k += 4) {
                const float4 wv = *(const float4*)&wrow[k];
                ws[(cbw + k + 0) * CHN + ow] = wv.x;
                ws[(cbw + k + 1) * CHN + ow] = wv.y;
                ws[(cbw + k + 2) * CHN + ow] = wv.z;
                ws[(cbw + k + 3) * CHN + ow] = wv.w;
            }
        }
        __syncthreads();
        #pragma unroll
        for (int c = 0; c < KC; ++c) {
            const float4 xa = *(const float4*)&xs[c * PXT + px0];
            const float4 xb = *(const float4*)&xs[c * PXT + px0 + 4];
            const float4 wa = *(const float4*)&ws[c * CHN + o0];
            const float4 wb = *(const float4*)&ws[c * CHN + o0 + 4];
            const float xv[8] = {xa.x, xa.y, xa.z, xa.w, xb.x, xb.y, xb.z, xb.w};
            const float wv[8] = {wa.x, wa.y, wa.z, wa.w, wb.x, wb.y, wb.z, wb.w};
            #pragma unroll
            for (int i = 0; i < 8; ++i)
                #pragma unroll
                for (int j = 0; j < 8; ++j)
                    acc[i][j] = fmaf(xv[i], wv[j], acc[i][j]);
        }
    }

    // epilogue: bias + ReLU + w2 dot -> per-(pixel, o-group) partial logits
    const float4 b1a = *(const float4*)&b1[o0];
    const float4 b1b = *(const float4*)&b1[o0 + 4];
    const float4 w0a = *(const float4*)&w2[o0];
    const float4 w0b = *(const float4*)&w2[o0 + 4];
    const float4 w1a = *(const float4*)&w2[CHN + o0];
    const float4 w1b = *(const float4*)&w2[CHN + o0 + 4];
    const float bbv[8] = {b1a.x, b1a.y, b1a.z, b1a.w, b1b.x, b1b.y, b1b.z, b1b.w};
    const float w0v[8] = {w0a.x, w0a.y, w0a.z, w0a.w, w0b.x, w0b.y, w0b.z, w0b.w};
    const float w1v[8] = {w1a.x, w1a.y, w1a.z, w1a.w, w1b.x, w1b.y, w1b.z, w1b.w};

    float l0p[8], l1p[8];
    #pragma unroll
    for (int i = 0; i < 8; ++i) {
        float l0 = 0.0f, l1 = 0.0f;
        #pragma unroll
        for (int j = 0; j < 8; ++j) {
            const float h  = acc[i][j] + bbv[j];
            const float rl = fmaxf(h, 0.0f);
            l0 = fmaf(rl, w0v[j], l0);
            l1 = fmaf(rl, w1v[j], l1);
        }
        l0p[i] = l0;
        l1p[i] = l1;
    }

    __syncthreads();  // xs no longer needed; red overlays it
    #pragma unroll
    for (int i = 0; i < 8; ++i) {
        red[(og * PXT + px0 + i) * 2 + 0] = l0p[i];
        red[(og * PXT + px0 + i) * 2 + 1] = l1p[i];
    }
    __syncthreads();

    if (t < PXT) {
        float l0 = b2[0], l1 = b2[1];
        #pragma unroll
        for (int g = 0; g < 16; ++g) {
            l0 += red[(g * PXT + t) * 2 + 0];
            l1 += red[(g * PXT + t) * 2 + 1];
        }
        // softmax over {l0, l1} (TEMPERATURE == 1)
        const float d  = l1 - l0;
        const float e  = __expf(d);        // d -> +inf: m0 -> 0; -inf: m0 -> 1
        const float m0 = 1.0f / (1.0f + e);
        const float m1 = 1.0f - m0;
        mout[(b * 2 + 0) * HWP + hw0 + t] = m0;
        mout[(b * 2 + 1) * HWP + hw0 + t] = m1;
    }
}

// ---------------------------------------------------------------------------
// Kernel 2: x0 = x * m0, x1 = x * m1.  One float4 per thread. Memory-bound:
// 302 MB read + 604 MB write (+ m from L2).
// ---------------------------------------------------------------------------
__global__ __launch_bounds__(256) void split_kernel(
    const float* __restrict__ x, const float* __restrict__ m,
    float* __restrict__ out0, float* __restrict__ out1)
{
    const unsigned g   = blockIdx.x * 256u + threadIdx.x;
    const unsigned e   = g * 4u;                  // < 75497472
    const unsigned bcs = CC * HWP;                // 4718592
    const unsigned b   = e / bcs;
    const unsigned r   = e - b * bcs;
    const unsigned hw  = r % HWP;                 // multiple of 4 -> aligned

    const float4 xv = *(const float4*)&x[e];
    const float4 m0 = *(const float4*)&m[(b * 2u + 0u) * HWP + hw];
    const float4 m1 = *(const float4*)&m[(b * 2u + 1u) * HWP + hw];

    float4 a, c;
    a.x = xv.x * m0.x; a.y = xv.y * m0.y; a.z = xv.z * m0.z; a.w = xv.w * m0.w;
    c.x = xv.x * m1.x; c.y = xv.y * m1.y; c.z = xv.z * m1.z; c.w = xv.w * m1.w;

    *(float4*)&out0[e] = a;
    *(float4*)&out1[e] = c;
}

extern "C" void kernel_launch(void* const* d_in, const int* in_sizes, int n_in,
                              void* d_out, int out_size, void* d_ws, size_t ws_size,
                              hipStream_t stream)
{
    const float* x  = (const float*)d_in[0];
    const float* w1 = (const float*)d_in[1];
    const float* b1 = (const float*)d_in[2];
    const float* w2 = (const float*)d_in[3];
    const float* b2 = (const float*)d_in[4];

    float* out  = (float*)d_out;
    float* out0 = out;
    float* out1 = out + (size_t)XSZ;
    float* mo   = out + (size_t)2 * XSZ;

    // 147456 pixels / 128 per block = 1152 blocks
    mask_head_kernel<<<(BB * HWP) / PXT, 256, 0, stream>>>(x, w1, b1, w2, b2, mo);
    // 75497472 / 4 / 256 = 73728 blocks
    split_kernel<<<XSZ / 4 / 256, 256, 0, stream>>>(x, mo, out0, out1);
}